// Round 1
// baseline (2428.973 us; speedup 1.0000x reference)
//
#include <hip/hip_runtime.h>

#define HH 2048
#define WW 2048
#define HWTOT 4194304
#define BIGL 4194304
#define CSZ 227
#define NCLS 4
#define MINSZ 64

// d_out layout (bytes). d_out = 64MB = 4 channels x 16MB.
#define OFF_LABA 0u
#define OFF_LABB (1u<<24)
#define OFF_ROIS (1u<<24)                  // reuses LABB region after CC
#define OFF_H1C  ((1u<<24) + 3538944u)
#define OFF_H2C  ((1u<<24) + 7077888u)
#define OFF_CAND ((1u<<24) + 9437184u)
#define OFF_COUNTS (2u<<24)
#define OFF_W2D  50331904u

struct Meta {
  int lids[16];
  int valid[16];
  int cls[16];
  int bby0[16], bby1[16], bbx0[16], bbx1[16];
};

// ---------------- prep: w2 -> f64 ----------------
__global__ __launch_bounds__(256) void prep_kernel(const float* __restrict__ w2,
                                                   double* __restrict__ w2d) {
  int i = blockIdx.x * 256 + threadIdx.x;
  if (i < 9216) w2d[i] = (double)w2[i];
}

// ---------------- fused cascade: conv1+relu -> conv2+relu -> conv3 -> threshold -> init labels
// f64 accumulation for conv2/conv3 (minimize our rounding vs XLA's f32 reference).
__global__ __launch_bounds__(256) void cascade_kernel(
    const float* __restrict__ x, const float* __restrict__ w1,
    const double* __restrict__ w2d, const float* __restrict__ w3,
    int* __restrict__ lab) {
  __shared__ float xs[36][36];
  __shared__ float h1s[8][34][35];
  __shared__ float w1s[32][9];
  __shared__ float w3s[32];

  const int tid = threadIdx.x;
  const int ox = blockIdx.x * 32, oy = blockIdx.y * 32;

  for (int i = tid; i < 288; i += 256) ((float*)w1s)[i] = w1[i];
  if (tid < 32) w3s[tid] = w3[tid];
  for (int i = tid; i < 36 * 36; i += 256) {
    int yy = i / 36, xx = i - yy * 36;
    int gy = oy - 2 + yy, gx = ox - 2 + xx;
    float v = 0.f;
    if ((unsigned)gy < (unsigned)HH && (unsigned)gx < (unsigned)WW) v = x[gy * WW + gx];
    xs[yy][xx] = v;
  }

  const int tx = tid & 31, ty0 = tid >> 5;  // thread owns rows ty0+8k, col tx
  double z[4] = {0.0, 0.0, 0.0, 0.0};

#pragma unroll 1
  for (int cog = 0; cog < 4; ++cog) {
    double acc[8][4];
#pragma unroll
    for (int j = 0; j < 8; ++j)
#pragma unroll
      for (int k2 = 0; k2 < 4; ++k2) acc[j][k2] = 0.0;

#pragma unroll 1
    for (int cig = 0; cig < 4; ++cig) {
      __syncthreads();  // prior conv2 reads done before h1s overwrite (also covers xs/w1s init)
      // conv1 (f32) for ci chunk [cig*8, cig*8+8) over 34x34 halo grid
      for (int i2 = tid; i2 < 34 * 34; i2 += 256) {
        int yy = i2 / 34, xx = i2 - yy * 34;
        int gy = oy - 1 + yy, gx = ox - 1 + xx;
        bool inb = ((unsigned)gy < (unsigned)HH) && ((unsigned)gx < (unsigned)WW);
        float a[9];
#pragma unroll
        for (int dy = 0; dy < 3; ++dy)
#pragma unroll
          for (int dx = 0; dx < 3; ++dx) a[dy * 3 + dx] = xs[yy + dy][xx + dx];
#pragma unroll 1
        for (int ci = 0; ci < 8; ++ci) {
          float s = 0.f;
#pragma unroll
          for (int t9 = 0; t9 < 9; ++t9) s += a[t9] * w1s[cig * 8 + ci][t9];
          h1s[ci][yy][xx] = (inb && (s > 0.f)) ? s : 0.f;
        }
      }
      __syncthreads();
      // conv2 partial sums (f64)
#pragma unroll 1
      for (int ci = 0; ci < 8; ++ci) {
#pragma unroll
        for (int dy = 0; dy < 3; ++dy)
#pragma unroll
          for (int dx = 0; dx < 3; ++dx) {
            double wv[8];
#pragma unroll
            for (int j = 0; j < 8; ++j)
              wv[j] = w2d[(cog * 8 + j) * 288 + (cig * 8 + ci) * 9 + dy * 3 + dx];
#pragma unroll
            for (int k2 = 0; k2 < 4; ++k2) {
              double v = (double)h1s[ci][ty0 + 8 * k2 + dy][tx + dx];
#pragma unroll
              for (int j = 0; j < 8; ++j) acc[j][k2] = fma(v, wv[j], acc[j][k2]);
            }
          }
      }
    }
    // relu + conv3 (1x1) accumulate into z
#pragma unroll
    for (int j = 0; j < 8; ++j) {
      double w3v = (double)w3s[cog * 8 + j];
#pragma unroll
      for (int k2 = 0; k2 < 4; ++k2) {
        double hv = acc[j][k2] > 0.0 ? acc[j][k2] : 0.0;
        z[k2] = fma(w3v, hv, z[k2]);
      }
    }
  }
  // sigmoid(z) > 0.5 in XLA f32 (0.5+0.5*tanh(0.5 z)) <=> z > 2^-23
#pragma unroll
  for (int k2 = 0; k2 < 4; ++k2) {
    int gy = oy + ty0 + 8 * k2, gx = ox + tx;
    int p = gy * WW + gx;
    lab[p] = (z[k2] > 1.1920928955078125e-7) ? p : BIGL;
  }
}

// ---------------- one CC min-propagation step ----------------
__global__ __launch_bounds__(256) void cc_kernel(const int* __restrict__ in,
                                                 int* __restrict__ out) {
  int t = blockIdx.x * 256 + threadIdx.x;
  int p = t * 4;
  int y = p >> 11, x = p & 2047;
  int4 c = *(const int4*)(in + p);
  int4 u = (y > 0) ? *(const int4*)(in + p - WW) : make_int4(BIGL, BIGL, BIGL, BIGL);
  int4 d = (y < HH - 1) ? *(const int4*)(in + p + WW) : make_int4(BIGL, BIGL, BIGL, BIGL);
  int lf = (x > 0) ? in[p - 1] : BIGL;
  int rt = (x + 4 < WW) ? in[p + 4] : BIGL;
  int4 r;
  r.x = (c.x == BIGL) ? BIGL : min(min(c.x, c.y), min(min(u.x, d.x), lf));
  r.y = (c.y == BIGL) ? BIGL : min(min(c.y, min(c.x, c.z)), min(u.y, d.y));
  r.z = (c.z == BIGL) ? BIGL : min(min(c.z, min(c.y, c.w)), min(u.z, d.z));
  r.w = (c.w == BIGL) ? BIGL : min(min(c.w, min(c.z, rt)), min(u.w, d.w));
  *(int4*)(out + p) = r;
}

// ---------------- histogram with run-length compression ----------------
__global__ __launch_bounds__(256) void hist_kernel(const int* __restrict__ lab,
                                                   int* __restrict__ counts) {
  int t = blockIdx.x * 256 + threadIdx.x;
  int p = t * 8;
  int4 a = *(const int4*)(lab + p), b = *(const int4*)(lab + p + 4);
  int v[8] = {a.x, a.y, a.z, a.w, b.x, b.y, b.z, b.w};
  int prev = -1, run = 0;
#pragma unroll
  for (int j = 0; j < 8; ++j) {
    int l = v[j];
    if (l == prev) {
      run++;
    } else {
      if (prev >= 0 && prev != BIGL) atomicAdd(&counts[prev], run);
      prev = l;
      run = 1;
    }
  }
  if (prev >= 0 && prev != BIGL) atomicAdd(&counts[prev], run);
}

// ---------------- collect labels with count >= MINSZ ----------------
__global__ __launch_bounds__(256) void cand_kernel(const int* __restrict__ counts,
                                                   int2* __restrict__ cand,
                                                   int* __restrict__ cand_count) {
  int i = blockIdx.x * 256 + threadIdx.x;
  if (i >= HWTOT) return;
  int c = counts[i];
  if (c >= MINSZ) {
    int j = atomicAdd(cand_count, 1);
    if (j < 65536) cand[j] = make_int2(c, i);
  }
}

// ---------------- top-16 by (count desc, label asc); init meta ----------------
__global__ __launch_bounds__(256) void top16_kernel(const int2* __restrict__ cand,
                                                    const int* __restrict__ cand_count,
                                                    Meta* __restrict__ meta) {
  __shared__ unsigned long long skey[256];
  __shared__ int sidx[256];
  __shared__ unsigned mark[2048];
  int tid = threadIdx.x;
  for (int i = tid; i < 2048; i += 256) mark[i] = 0u;
  int n = *cand_count;
  if (n > 65536) n = 65536;
  __syncthreads();
  for (int r = 0; r < 16; ++r) {
    unsigned long long best = 0ull;
    int bi = -1;
    for (int i = tid; i < n; i += 256) {
      if (mark[i >> 5] & (1u << (i & 31))) continue;
      int2 c = cand[i];
      unsigned long long key =
          ((unsigned long long)(unsigned)c.x << 32) | (unsigned)(BIGL - c.y);
      if (key > best) { best = key; bi = i; }
    }
    skey[tid] = best;
    sidx[tid] = bi;
    __syncthreads();
    for (int s = 128; s > 0; s >>= 1) {
      if (tid < s && skey[tid + s] > skey[tid]) {
        skey[tid] = skey[tid + s];
        sidx[tid] = sidx[tid + s];
      }
      __syncthreads();
    }
    if (tid == 0) {
      if (r < n) {
        int bidx = sidx[0];
        int2 c = cand[bidx];
        meta->lids[r] = c.y;
        meta->valid[r] = 1;
        mark[bidx >> 5] |= (1u << (bidx & 31));
      } else {
        meta->lids[r] = -1;
        meta->valid[r] = 0;
      }
    }
    __syncthreads();
  }
  if (tid < 16) {
    meta->bby0[tid] = HH; meta->bby1[tid] = -1;
    meta->bbx0[tid] = WW; meta->bbx1[tid] = -1;
    meta->cls[tid] = 0;
  }
}

// ---------------- bounding boxes of selected labels ----------------
__global__ __launch_bounds__(256) void bbox_kernel(const int* __restrict__ lab,
                                                   Meta* __restrict__ meta) {
  __shared__ int lid_s[16];
  __shared__ int by0[16], by1[16], bx0[16], bx1[16];
  int tid = threadIdx.x;
  if (tid < 16) {
    lid_s[tid] = meta->lids[tid];
    by0[tid] = HH; by1[tid] = -1; bx0[tid] = WW; bx1[tid] = -1;
  }
  __syncthreads();
  int t = blockIdx.x * 256 + tid;
  int p = t * 8;
  int y = p >> 11, xbase = p & 2047;
  int4 a = *(const int4*)(lab + p), b = *(const int4*)(lab + p + 4);
  int v[8] = {a.x, a.y, a.z, a.w, b.x, b.y, b.z, b.w};
  int prev = BIGL, kprev = -1, xs = 0, xe = 0;
#pragma unroll
  for (int j = 0; j < 8; ++j) {
    int l = v[j];
    if (l == prev) { xe = xbase + j; continue; }
    if (kprev >= 0) {
      atomicMin(&by0[kprev], y); atomicMax(&by1[kprev], y);
      atomicMin(&bx0[kprev], xs); atomicMax(&bx1[kprev], xe);
    }
    prev = l; xs = xe = xbase + j; kprev = -1;
    if (l != BIGL) {
      for (int k = 0; k < 16; ++k)
        if (lid_s[k] == l) { kprev = k; break; }
    }
  }
  if (kprev >= 0) {
    atomicMin(&by0[kprev], y); atomicMax(&by1[kprev], y);
    atomicMin(&bx0[kprev], xs); atomicMax(&bx1[kprev], xe);
  }
  __syncthreads();
  if (tid < 16 && by1[tid] >= 0) {
    atomicMin(&meta->bby0[tid], by0[tid]); atomicMax(&meta->bby1[tid], by1[tid]);
    atomicMin(&meta->bbx0[tid], bx0[tid]); atomicMax(&meta->bbx1[tid], bx1[tid]);
  }
}

// ---------------- ROI bilinear resize to 227x227 ----------------
__global__ __launch_bounds__(256) void roi_kernel(const float* __restrict__ img,
                                                  const Meta* __restrict__ meta,
                                                  float* __restrict__ rois) {
  int k = blockIdx.y, i = blockIdx.x, j = threadIdx.x;
  if (j >= CSZ) return;
  if (!meta->valid[k]) return;
  float y0 = (float)meta->bby0[k], y1 = (float)meta->bby1[k];
  float x0 = (float)meta->bbx0[k], x1 = (float)meta->bbx1[k];
  float ti = (float)i / 226.f, tj = (float)j / 226.f;
  float gy = y0 + ti * (y1 - y0);
  float gx = x0 + tj * (x1 - x0);
  int yf = (int)floorf(gy); yf = yf < 0 ? 0 : (yf > HH - 2 ? HH - 2 : yf);
  int xf = (int)floorf(gx); xf = xf < 0 ? 0 : (xf > WW - 2 ? WW - 2 : xf);
  float fy = gy - (float)yf, fx = gx - (float)xf;
  const float* r0 = img + yf * WW + xf;
  float v00 = r0[0], v01 = r0[1], v10 = r0[WW], v11 = r0[WW + 1];
  float val = (1.f - fy) * ((1.f - fx) * v00 + fx * v01) +
              fy * ((1.f - fx) * v10 + fx * v11);
  rois[(k * CSZ + i) * CSZ + j] = val;
}

// ---------------- classifier conv1: 1->16, 7x7, stride 4, VALID ----------------
__global__ __launch_bounds__(256) void cconv1_kernel(const float* __restrict__ rois,
                                                     const float* __restrict__ cw1,
                                                     const Meta* __restrict__ meta,
                                                     float* __restrict__ h1c) {
  int k = blockIdx.y, oy = blockIdx.x;
  if (!meta->valid[k]) return;
  const float* roi = rois + k * CSZ * CSZ;
  for (int idx = threadIdx.x; idx < 16 * 56; idx += 256) {
    int ch = idx / 56, ox = idx - ch * 56;
    const float* wp = cw1 + ch * 49;
    float s = 0.f;
#pragma unroll
    for (int dy = 0; dy < 7; ++dy)
#pragma unroll
      for (int dx = 0; dx < 7; ++dx)
        s += roi[(oy * 4 + dy) * CSZ + ox * 4 + dx] * wp[dy * 7 + dx];
    h1c[((k * 16 + ch) * 56 + oy) * 56 + ox] = s > 0.f ? s : 0.f;
  }
}

// ---------------- classifier conv2: 16->32, 3x3, stride 2, VALID ----------------
__global__ __launch_bounds__(256) void cconv2_kernel(const float* __restrict__ h1c,
                                                     const float* __restrict__ cw2,
                                                     const Meta* __restrict__ meta,
                                                     float* __restrict__ h2c) {
  int k = blockIdx.y, oy = blockIdx.x;
  if (!meta->valid[k]) return;
  for (int idx = threadIdx.x; idx < 32 * 27; idx += 256) {
    int ch = idx / 27, ox = idx - ch * 27;
    float s = 0.f;
    for (int ci = 0; ci < 16; ++ci) {
      const float* hp = h1c + ((k * 16 + ci) * 56 + oy * 2) * 56 + ox * 2;
      const float* wp = cw2 + (ch * 16 + ci) * 9;
#pragma unroll
      for (int dy = 0; dy < 3; ++dy)
#pragma unroll
        for (int dx = 0; dx < 3; ++dx) s += hp[dy * 56 + dx] * wp[dy * 3 + dx];
    }
    h2c[((k * 32 + ch) * 27 + oy) * 27 + ox] = s > 0.f ? s : 0.f;
  }
}

// ---------------- global mean pool + fc + argmax ----------------
__global__ __launch_bounds__(256) void poolfc_kernel(const float* __restrict__ h2c,
                                                     const float* __restrict__ fc,
                                                     Meta* __restrict__ meta) {
  int k = blockIdx.x;
  if (!meta->valid[k]) return;
  __shared__ float sums[8][32];
  int tid = threadIdx.x;
  int c = tid & 31, part = tid >> 5;
  float s = 0.f;
  const float* hp = h2c + (k * 32 + c) * 729;
  for (int j = part; j < 729; j += 8) s += hp[j];
  sums[part][c] = s;
  __syncthreads();
  if (tid < 32) {
    float g = 0.f;
#pragma unroll
    for (int p2 = 0; p2 < 8; ++p2) g += sums[p2][tid];
    sums[0][tid] = g / 729.f;
  }
  __syncthreads();
  if (tid == 0) {
    float best = -1e30f;
    int bi = 0;
    for (int j = 0; j < NCLS; ++j) {
      float lg = 0.f;
      for (int c2 = 0; c2 < 32; ++c2) lg += sums[0][c2] * fc[c2 * NCLS + j];
      if (lg > best) { best = lg; bi = j; }
    }
    meta->cls[k] = bi;
  }
}

// ---------------- final: write 4-channel one-hot masks ----------------
// labf aliases out channel 0: read labels (as float4 bits) strictly before stores.
__global__ __launch_bounds__(256) void final_kernel(const float* labf,
                                                    const Meta* __restrict__ meta,
                                                    float* out) {
  __shared__ int lid_s[16];
  __shared__ int cls_s[16];
  int tid = threadIdx.x;
  if (tid < 16) {
    lid_s[tid] = meta->valid[tid] ? meta->lids[tid] : -1;
    cls_s[tid] = meta->cls[tid];
  }
  __syncthreads();
  int t = blockIdx.x * 256 + tid;
  int p = t * 4;
  float4 lf = *(const float4*)(labf + p);
  int l4[4] = {__float_as_int(lf.x), __float_as_int(lf.y), __float_as_int(lf.z),
               __float_as_int(lf.w)};
  int cj[4];
#pragma unroll
  for (int j = 0; j < 4; ++j) {
    cj[j] = -1;
    int l = l4[j];
    if (l != BIGL) {
      for (int k = 0; k < 16; ++k)
        if (lid_s[k] == l) { cj[j] = cls_s[k]; break; }
    }
  }
#pragma unroll
  for (int c = 0; c < 4; ++c) {
    float4 w4 = make_float4(cj[0] == c ? 1.f : 0.f, cj[1] == c ? 1.f : 0.f,
                            cj[2] == c ? 1.f : 0.f, cj[3] == c ? 1.f : 0.f);
    *(float4*)(out + (size_t)c * HWTOT + p) = w4;
  }
}

extern "C" void kernel_launch(void* const* d_in, const int* in_sizes, int n_in,
                              void* d_out, int out_size, void* d_ws, size_t ws_size,
                              hipStream_t stream) {
  const float* x = (const float*)d_in[0];
  const float* w1 = (const float*)d_in[1];
  const float* w2 = (const float*)d_in[2];
  const float* w3 = (const float*)d_in[3];
  const float* cw1 = (const float*)d_in[4];
  const float* cw2 = (const float*)d_in[5];
  const float* fc = (const float*)d_in[6];

  char* base = (char*)d_out;
  int* lab_a = (int*)(base + OFF_LABA);
  int* lab_b = (int*)(base + OFF_LABB);
  float* rois = (float*)(base + OFF_ROIS);
  float* h1c = (float*)(base + OFF_H1C);
  float* h2c = (float*)(base + OFF_H2C);
  int2* cand = (int2*)(base + OFF_CAND);
  int* counts = (int*)(base + OFF_COUNTS);
  double* w2d = (double*)(base + OFF_W2D);
  int* cand_count = (int*)d_ws;
  Meta* meta = (Meta*)((char*)d_ws + 256);

  hipMemsetAsync(counts, 0, (size_t)(HWTOT + 1) * sizeof(int), stream);
  hipMemsetAsync(cand_count, 0, sizeof(int), stream);

  prep_kernel<<<36, 256, 0, stream>>>(w2, w2d);
  cascade_kernel<<<dim3(64, 64), 256, 0, stream>>>(x, w1, w2d, w3, lab_a);

  for (int it = 0; it < 64; ++it) {
    const int* src = (it & 1) ? lab_b : lab_a;
    int* dst = (it & 1) ? lab_a : lab_b;
    cc_kernel<<<4096, 256, 0, stream>>>(src, dst);
  }
  // 64 steps (even) -> final labels in lab_a

  hist_kernel<<<2048, 256, 0, stream>>>(lab_a, counts);
  cand_kernel<<<16384, 256, 0, stream>>>(counts, cand, cand_count);
  top16_kernel<<<1, 256, 0, stream>>>(cand, cand_count, meta);
  bbox_kernel<<<2048, 256, 0, stream>>>(lab_a, meta);
  roi_kernel<<<dim3(CSZ, 16), 256, 0, stream>>>(x, meta, rois);
  cconv1_kernel<<<dim3(56, 16), 256, 0, stream>>>(rois, cw1, meta, h1c);
  cconv2_kernel<<<dim3(27, 16), 256, 0, stream>>>(h1c, cw2, meta, h2c);
  poolfc_kernel<<<16, 256, 0, stream>>>(h2c, fc, meta);
  final_kernel<<<4096, 256, 0, stream>>>((const float*)d_out, meta, (float*)d_out);
}

// Round 2
// 1532.985 us; speedup vs baseline: 1.5845x; 1.5845x over previous
//
#include <hip/hip_runtime.h>

#define HH 2048
#define WW 2048
#define HWTOT 4194304
#define BIGL 4194304
#define CSZ 227
#define NCLS 4
#define MINSZ 64
#define TF 1.1920928955078125e-7f
#define EPSB 5e-3f
#define LISTCAP 4000000

// d_out layout (bytes). d_out = 64MB = 4 regions x 16MB.
#define OFF_LABA 0u
#define OFF_LABB (1u<<24)
#define OFF_ROIS (1u<<24)                  // reuses LABB region after CC
#define OFF_H1C  ((1u<<24) + 3538944u)
#define OFF_H2C  ((1u<<24) + 7077888u)
#define OFF_CAND ((1u<<24) + 9437184u)
#define OFF_COUNTS (2u<<24)
#define OFF_W2T  ((3u<<24) + 4096u)
#define OFF_LIST ((3u<<24) + 131072u)

struct Meta {
  int lids[16];
  int valid[16];
  int cls[16];
  int bby0[16], bby1[16], bbx0[16], bbx1[16];
};

// ---------------- prep: transpose w2 [j][tap] -> w2t [tap][j] ----------------
__global__ __launch_bounds__(256) void prep_kernel(const float* __restrict__ w2,
                                                   float* __restrict__ w2t) {
  int i = blockIdx.x * 256 + threadIdx.x;
  if (i < 9216) {
    int j = i & 31, tap = i >> 5;  // tap = ci*9 + dy*3 + dx
    w2t[tap * 32 + j] = w2[j * 288 + tap];
  }
}

// ---------------- fused cascade (f32) + boundary-band list ----------------
__global__ __launch_bounds__(256) void cascade_kernel(
    const float* __restrict__ x, const float* __restrict__ w1,
    const float* __restrict__ w2t, const float* __restrict__ w3,
    int* __restrict__ lab, int* __restrict__ list, int* __restrict__ list_count) {
  __shared__ float xs[36][36];
  __shared__ float h1s[8][34][36];
  __shared__ float w1s[32][9];
  __shared__ float w3s[32];

  const int tid = threadIdx.x;
  const int ox = blockIdx.x * 32, oy = blockIdx.y * 32;

  for (int i = tid; i < 288; i += 256) ((float*)w1s)[i] = w1[i];
  if (tid < 32) w3s[tid] = w3[tid];
  for (int i = tid; i < 36 * 36; i += 256) {
    int yy = i / 36, xx = i - yy * 36;
    int gy = oy - 2 + yy, gx = ox - 2 + xx;
    float v = 0.f;
    if ((unsigned)gy < (unsigned)HH && (unsigned)gx < (unsigned)WW) v = x[gy * WW + gx];
    xs[yy][xx] = v;
  }

  const int r = tid >> 3;          // output row 0..31
  const int cg = (tid & 7) * 4;    // output col group start
  float z[4] = {0.f, 0.f, 0.f, 0.f};

#pragma unroll 1
  for (int cog = 0; cog < 2; ++cog) {
    float acc[16][4];
#pragma unroll
    for (int j = 0; j < 16; ++j)
#pragma unroll
      for (int c = 0; c < 4; ++c) acc[j][c] = 0.f;

#pragma unroll 1
    for (int cig = 0; cig < 4; ++cig) {
      __syncthreads();  // prior conv2 reads done before h1s overwrite (also covers staging)
      // conv1 (f32, exact fmaf chain t9=0..8) for ci in [cig*8, cig*8+8)
#pragma unroll 1
      for (int i2 = tid; i2 < 34 * 34; i2 += 256) {
        int yy = i2 / 34, xx = i2 - yy * 34;
        int gy = oy - 1 + yy, gx = ox - 1 + xx;
        bool inb = ((unsigned)gy < (unsigned)HH) && ((unsigned)gx < (unsigned)WW);
        float a[9];
#pragma unroll
        for (int dy = 0; dy < 3; ++dy)
#pragma unroll
          for (int dx = 0; dx < 3; ++dx) a[dy * 3 + dx] = xs[yy + dy][xx + dx];
#pragma unroll 1
        for (int ci8 = 0; ci8 < 8; ++ci8) {
          const float* wp = &w1s[cig * 8 + ci8][0];
          float s = 0.f;
#pragma unroll
          for (int t9 = 0; t9 < 9; ++t9) s = fmaf(a[t9], wp[t9], s);
          h1s[ci8][yy][xx] = (inb && (s > 0.f)) ? s : 0.f;
        }
      }
      __syncthreads();
      // conv2 partial sums (f32), h via aligned b128, w via uniform float4
#pragma unroll 1
      for (int ci8 = 0; ci8 < 8; ++ci8) {
#pragma unroll
        for (int dy = 0; dy < 3; ++dy) {
          float4 hA = *(const float4*)&h1s[ci8][r + dy][cg];
          float4 hB = *(const float4*)&h1s[ci8][r + dy][cg + 4];
          float hv[7] = {hA.x, hA.y, hA.z, hA.w, hB.x, hB.y, hB.z};
          const float* wp = w2t + ((cig * 8 + ci8) * 9 + dy * 3) * 32 + cog * 16;
#pragma unroll
          for (int dx = 0; dx < 3; ++dx) {
            const float4* wq = (const float4*)(wp + dx * 32);
            float4 wA = wq[0], wB = wq[1], wC = wq[2], wD = wq[3];
            float wv[16] = {wA.x, wA.y, wA.z, wA.w, wB.x, wB.y, wB.z, wB.w,
                            wC.x, wC.y, wC.z, wC.w, wD.x, wD.y, wD.z, wD.w};
#pragma unroll
            for (int j = 0; j < 16; ++j) {
              float wj = wv[j];
#pragma unroll
              for (int c = 0; c < 4; ++c)
                acc[j][c] = fmaf(hv[c + dx], wj, acc[j][c]);
            }
          }
        }
      }
    }
    // relu + conv3 (1x1), j ascending
#pragma unroll
    for (int j = 0; j < 16; ++j) {
      float w3v = w3s[cog * 16 + j];
#pragma unroll
      for (int c = 0; c < 4; ++c)
        z[c] = fmaf(w3v, fmaxf(acc[j][c], 0.f), z[c]);
    }
  }

  // decide: sigmoid(z)>0.5 (XLA f32) <=> z > 2^-23; band pixels -> recheck list
  int lane = tid & 63;
#pragma unroll
  for (int c = 0; c < 4; ++c) {
    int gy = oy + r, gx = ox + cg + c;
    int p = gy * WW + gx;
    lab[p] = (z[c] > TF) ? p : BIGL;
    bool need = fabsf(z[c] - TF) < EPSB;
    unsigned long long m = __ballot(need);
    if (m) {
      int cnt = __popcll(m);
      int prefix = __popcll(m & ((1ull << lane) - 1ull));
      int base = 0;
      if (need && prefix == 0) base = atomicAdd(list_count, cnt);
      int src_lane = __ffsll((long long)m) - 1;
      base = __shfl(base, src_lane);
      if (need && base + prefix < LISTCAP) list[base + prefix] = p;
    }
  }
}

// ---------------- f64 recheck of band pixels (bit-identical to round-1 kernel) ----
__global__ __launch_bounds__(256) void recheck_kernel(
    const float* __restrict__ x, const float* __restrict__ w1,
    const float* __restrict__ w2, const float* __restrict__ w3,
    const int* __restrict__ list, const int* __restrict__ list_count,
    int* __restrict__ lab) {
  int n = *list_count;
  if (n > LISTCAP) n = LISTCAP;
  for (int i = blockIdx.x * 256 + threadIdx.x; i < n; i += 2048 * 256) {
    int p = list[i];
    int py = p >> 11, px = p & 2047;
    float xv[5][5];
#pragma unroll
    for (int u = 0; u < 5; ++u)
#pragma unroll
      for (int v = 0; v < 5; ++v) {
        int gy = py - 2 + u, gx = px - 2 + v;
        xv[u][v] = ((unsigned)gy < (unsigned)HH && (unsigned)gx < (unsigned)WW)
                       ? x[gy * WW + gx] : 0.f;
      }
    double acc2[32];
#pragma unroll
    for (int j = 0; j < 32; ++j) acc2[j] = 0.0;
#pragma unroll 1
    for (int ci = 0; ci < 32; ++ci) {
      float h1v[3][3];
#pragma unroll
      for (int u = 0; u < 3; ++u)
#pragma unroll
        for (int v = 0; v < 3; ++v) {
          int gy = py - 1 + u, gx = px - 1 + v;
          float s = 0.f;
#pragma unroll
          for (int t9 = 0; t9 < 9; ++t9)
            s = fmaf(xv[u + t9 / 3][v + t9 % 3], w1[ci * 9 + t9], s);
          bool inb = ((unsigned)gy < (unsigned)HH) && ((unsigned)gx < (unsigned)WW);
          h1v[u][v] = (inb && (s > 0.f)) ? s : 0.f;
        }
#pragma unroll
      for (int dy = 0; dy < 3; ++dy)
#pragma unroll
        for (int dx = 0; dx < 3; ++dx) {
          double hd = (double)h1v[dy][dx];
#pragma unroll
          for (int j = 0; j < 32; ++j)
            acc2[j] = fma(hd, (double)w2[j * 288 + ci * 9 + dy * 3 + dx], acc2[j]);
        }
    }
    double zz = 0.0;
#pragma unroll
    for (int j = 0; j < 32; ++j)
      zz = fma((double)w3[j], acc2[j] > 0.0 ? acc2[j] : 0.0, zz);
    lab[p] = (zz > 1.1920928955078125e-7) ? p : BIGL;
  }
}

// ---------------- CC: 8 exact min-propagation steps per launch (LDS, halo 8) ----
__global__ __launch_bounds__(256) void cc8_kernel(const int* __restrict__ in,
                                                  int* __restrict__ out) {
  __shared__ __align__(16) int buf[2][6400];  // 2 x 80x80
  const int tid = threadIdx.x;
  const int bx = blockIdx.x & 31, by = blockIdx.x >> 5;
  const int ox = bx * 64 - 8, oy = by * 64 - 8;

  for (int i = tid; i < 1600; i += 256) {
    int row = i / 20, c4 = (i - row * 20) * 4;
    int gy = oy + row, gx0 = ox + c4;
    int4 v = make_int4(BIGL, BIGL, BIGL, BIGL);
    if ((unsigned)gy < (unsigned)HH) {
      if (gx0 >= 0 && gx0 <= WW - 4) {
        v = *(const int4*)(in + gy * WW + gx0);
      } else {
        if ((unsigned)(gx0 + 0) < (unsigned)WW) v.x = in[gy * WW + gx0 + 0];
        if ((unsigned)(gx0 + 1) < (unsigned)WW) v.y = in[gy * WW + gx0 + 1];
        if ((unsigned)(gx0 + 2) < (unsigned)WW) v.z = in[gy * WW + gx0 + 2];
        if ((unsigned)(gx0 + 3) < (unsigned)WW) v.w = in[gy * WW + gx0 + 3];
      }
    }
    *(int4*)&buf[0][row * 80 + c4] = v;
  }
  __syncthreads();

#pragma unroll 1
  for (int s = 0; s < 8; ++s) {
    const int cur = s & 1, nxt = cur ^ 1;
    for (int i = tid; i < 1600; i += 256) {
      int row = i / 20, c4 = (i - row * 20) * 4;
      int base = row * 80 + c4;
      int4 c = *(const int4*)&buf[cur][base];
      int4 u = (row > 0) ? *(const int4*)&buf[cur][base - 80]
                         : make_int4(BIGL, BIGL, BIGL, BIGL);
      int4 d = (row < 79) ? *(const int4*)&buf[cur][base + 80]
                          : make_int4(BIGL, BIGL, BIGL, BIGL);
      int lf = (c4 > 0) ? buf[cur][base - 1] : BIGL;
      int rt = (c4 < 76) ? buf[cur][base + 4] : BIGL;
      int4 r;
      r.x = (c.x == BIGL) ? BIGL : min(min(c.x, c.y), min(min(u.x, d.x), lf));
      r.y = (c.y == BIGL) ? BIGL : min(min(c.y, min(c.x, c.z)), min(u.y, d.y));
      r.z = (c.z == BIGL) ? BIGL : min(min(c.z, min(c.y, c.w)), min(u.z, d.z));
      r.w = (c.w == BIGL) ? BIGL : min(min(c.w, min(c.z, rt)), min(u.w, d.w));
      *(int4*)&buf[nxt][base] = r;
    }
    __syncthreads();
  }

  // 8 steps -> result in buf[0]; store central 64x64
  for (int i = tid; i < 1024; i += 256) {
    int row = i >> 4, c4 = (i & 15) * 4;
    int gy = oy + 8 + row, gx = ox + 8 + c4;
    *(int4*)(out + gy * WW + gx) = *(const int4*)&buf[0][(row + 8) * 80 + (c4 + 8)];
  }
}

// ---------------- histogram with run-length compression ----------------
__global__ __launch_bounds__(256) void hist_kernel(const int* __restrict__ lab,
                                                   int* __restrict__ counts) {
  int t = blockIdx.x * 256 + threadIdx.x;
  int p = t * 8;
  int4 a = *(const int4*)(lab + p), b = *(const int4*)(lab + p + 4);
  int v[8] = {a.x, a.y, a.z, a.w, b.x, b.y, b.z, b.w};
  int prev = -1, run = 0;
#pragma unroll
  for (int j = 0; j < 8; ++j) {
    int l = v[j];
    if (l == prev) {
      run++;
    } else {
      if (prev >= 0 && prev != BIGL) atomicAdd(&counts[prev], run);
      prev = l;
      run = 1;
    }
  }
  if (prev >= 0 && prev != BIGL) atomicAdd(&counts[prev], run);
}

// ---------------- collect labels with count >= MINSZ ----------------
__global__ __launch_bounds__(256) void cand_kernel(const int* __restrict__ counts,
                                                   int2* __restrict__ cand,
                                                   int* __restrict__ cand_count) {
  int i = blockIdx.x * 256 + threadIdx.x;
  if (i >= HWTOT) return;
  int c = counts[i];
  if (c >= MINSZ) {
    int j = atomicAdd(cand_count, 1);
    if (j < 65536) cand[j] = make_int2(c, i);
  }
}

// ---------------- top-16 by (count desc, label asc); init meta ----------------
__global__ __launch_bounds__(256) void top16_kernel(const int2* __restrict__ cand,
                                                    const int* __restrict__ cand_count,
                                                    Meta* __restrict__ meta) {
  __shared__ unsigned long long skey[256];
  __shared__ int sidx[256];
  __shared__ unsigned mark[2048];
  int tid = threadIdx.x;
  for (int i = tid; i < 2048; i += 256) mark[i] = 0u;
  int n = *cand_count;
  if (n > 65536) n = 65536;
  __syncthreads();
  for (int r = 0; r < 16; ++r) {
    unsigned long long best = 0ull;
    int bi = -1;
    for (int i = tid; i < n; i += 256) {
      if (mark[i >> 5] & (1u << (i & 31))) continue;
      int2 c = cand[i];
      unsigned long long key =
          ((unsigned long long)(unsigned)c.x << 32) | (unsigned)(BIGL - c.y);
      if (key > best) { best = key; bi = i; }
    }
    skey[tid] = best;
    sidx[tid] = bi;
    __syncthreads();
    for (int s = 128; s > 0; s >>= 1) {
      if (tid < s && skey[tid + s] > skey[tid]) {
        skey[tid] = skey[tid + s];
        sidx[tid] = sidx[tid + s];
      }
      __syncthreads();
    }
    if (tid == 0) {
      if (r < n) {
        int bidx = sidx[0];
        int2 c = cand[bidx];
        meta->lids[r] = c.y;
        meta->valid[r] = 1;
        mark[bidx >> 5] |= (1u << (bidx & 31));
      } else {
        meta->lids[r] = -1;
        meta->valid[r] = 0;
      }
    }
    __syncthreads();
  }
  if (tid < 16) {
    meta->bby0[tid] = HH; meta->bby1[tid] = -1;
    meta->bbx0[tid] = WW; meta->bbx1[tid] = -1;
    meta->cls[tid] = 0;
  }
}

// ---------------- bounding boxes of selected labels ----------------
__global__ __launch_bounds__(256) void bbox_kernel(const int* __restrict__ lab,
                                                   Meta* __restrict__ meta) {
  __shared__ int lid_s[16];
  __shared__ int by0[16], by1[16], bx0[16], bx1[16];
  int tid = threadIdx.x;
  if (tid < 16) {
    lid_s[tid] = meta->lids[tid];
    by0[tid] = HH; by1[tid] = -1; bx0[tid] = WW; bx1[tid] = -1;
  }
  __syncthreads();
  int t = blockIdx.x * 256 + tid;
  int p = t * 8;
  int y = p >> 11, xbase = p & 2047;
  int4 a = *(const int4*)(lab + p), b = *(const int4*)(lab + p + 4);
  int v[8] = {a.x, a.y, a.z, a.w, b.x, b.y, b.z, b.w};
  int prev = BIGL, kprev = -1, xs = 0, xe = 0;
#pragma unroll
  for (int j = 0; j < 8; ++j) {
    int l = v[j];
    if (l == prev) { xe = xbase + j; continue; }
    if (kprev >= 0) {
      atomicMin(&by0[kprev], y); atomicMax(&by1[kprev], y);
      atomicMin(&bx0[kprev], xs); atomicMax(&bx1[kprev], xe);
    }
    prev = l; xs = xe = xbase + j; kprev = -1;
    if (l != BIGL) {
      for (int k = 0; k < 16; ++k)
        if (lid_s[k] == l) { kprev = k; break; }
    }
  }
  if (kprev >= 0) {
    atomicMin(&by0[kprev], y); atomicMax(&by1[kprev], y);
    atomicMin(&bx0[kprev], xs); atomicMax(&bx1[kprev], xe);
  }
  __syncthreads();
  if (tid < 16 && by1[tid] >= 0) {
    atomicMin(&meta->bby0[tid], by0[tid]); atomicMax(&meta->bby1[tid], by1[tid]);
    atomicMin(&meta->bbx0[tid], bx0[tid]); atomicMax(&meta->bbx1[tid], bx1[tid]);
  }
}

// ---------------- ROI bilinear resize to 227x227 ----------------
__global__ __launch_bounds__(256) void roi_kernel(const float* __restrict__ img,
                                                  const Meta* __restrict__ meta,
                                                  float* __restrict__ rois) {
  int k = blockIdx.y, i = blockIdx.x, j = threadIdx.x;
  if (j >= CSZ) return;
  if (!meta->valid[k]) return;
  float y0 = (float)meta->bby0[k], y1 = (float)meta->bby1[k];
  float x0 = (float)meta->bbx0[k], x1 = (float)meta->bbx1[k];
  float ti = (float)i / 226.f, tj = (float)j / 226.f;
  float gy = y0 + ti * (y1 - y0);
  float gx = x0 + tj * (x1 - x0);
  int yf = (int)floorf(gy); yf = yf < 0 ? 0 : (yf > HH - 2 ? HH - 2 : yf);
  int xf = (int)floorf(gx); xf = xf < 0 ? 0 : (xf > WW - 2 ? WW - 2 : xf);
  float fy = gy - (float)yf, fx = gx - (float)xf;
  const float* r0 = img + yf * WW + xf;
  float v00 = r0[0], v01 = r0[1], v10 = r0[WW], v11 = r0[WW + 1];
  float val = (1.f - fy) * ((1.f - fx) * v00 + fx * v01) +
              fy * ((1.f - fx) * v10 + fx * v11);
  rois[(k * CSZ + i) * CSZ + j] = val;
}

// ---------------- classifier conv1: 1->16, 7x7, stride 4, VALID ----------------
__global__ __launch_bounds__(256) void cconv1_kernel(const float* __restrict__ rois,
                                                     const float* __restrict__ cw1,
                                                     const Meta* __restrict__ meta,
                                                     float* __restrict__ h1c) {
  int k = blockIdx.y, oy = blockIdx.x;
  if (!meta->valid[k]) return;
  const float* roi = rois + k * CSZ * CSZ;
  for (int idx = threadIdx.x; idx < 16 * 56; idx += 256) {
    int ch = idx / 56, ox = idx - ch * 56;
    const float* wp = cw1 + ch * 49;
    float s = 0.f;
#pragma unroll
    for (int dy = 0; dy < 7; ++dy)
#pragma unroll
      for (int dx = 0; dx < 7; ++dx)
        s += roi[(oy * 4 + dy) * CSZ + ox * 4 + dx] * wp[dy * 7 + dx];
    h1c[((k * 16 + ch) * 56 + oy) * 56 + ox] = s > 0.f ? s : 0.f;
  }
}

// ---------------- classifier conv2: 16->32, 3x3, stride 2, VALID ----------------
__global__ __launch_bounds__(256) void cconv2_kernel(const float* __restrict__ h1c,
                                                     const float* __restrict__ cw2,
                                                     const Meta* __restrict__ meta,
                                                     float* __restrict__ h2c) {
  int k = blockIdx.y, oy = blockIdx.x;
  if (!meta->valid[k]) return;
  for (int idx = threadIdx.x; idx < 32 * 27; idx += 256) {
    int ch = idx / 27, ox = idx - ch * 27;
    float s = 0.f;
    for (int ci = 0; ci < 16; ++ci) {
      const float* hp = h1c + ((k * 16 + ci) * 56 + oy * 2) * 56 + ox * 2;
      const float* wp = cw2 + (ch * 16 + ci) * 9;
#pragma unroll
      for (int dy = 0; dy < 3; ++dy)
#pragma unroll
        for (int dx = 0; dx < 3; ++dx) s += hp[dy * 56 + dx] * wp[dy * 3 + dx];
    }
    h2c[((k * 32 + ch) * 27 + oy) * 27 + ox] = s > 0.f ? s : 0.f;
  }
}

// ---------------- global mean pool + fc + argmax ----------------
__global__ __launch_bounds__(256) void poolfc_kernel(const float* __restrict__ h2c,
                                                     const float* __restrict__ fc,
                                                     Meta* __restrict__ meta) {
  int k = blockIdx.x;
  if (!meta->valid[k]) return;
  __shared__ float sums[8][32];
  int tid = threadIdx.x;
  int c = tid & 31, part = tid >> 5;
  float s = 0.f;
  const float* hp = h2c + (k * 32 + c) * 729;
  for (int j = part; j < 729; j += 8) s += hp[j];
  sums[part][c] = s;
  __syncthreads();
  if (tid < 32) {
    float g = 0.f;
#pragma unroll
    for (int p2 = 0; p2 < 8; ++p2) g += sums[p2][tid];
    sums[0][tid] = g / 729.f;
  }
  __syncthreads();
  if (tid == 0) {
    float best = -1e30f;
    int bi = 0;
    for (int j = 0; j < NCLS; ++j) {
      float lg = 0.f;
      for (int c2 = 0; c2 < 32; ++c2) lg += sums[0][c2] * fc[c2 * NCLS + j];
      if (lg > best) { best = lg; bi = j; }
    }
    meta->cls[k] = bi;
  }
}

// ---------------- final: write 4-channel one-hot masks ----------------
__global__ __launch_bounds__(256) void final_kernel(const float* labf,
                                                    const Meta* __restrict__ meta,
                                                    float* out) {
  __shared__ int lid_s[16];
  __shared__ int cls_s[16];
  int tid = threadIdx.x;
  if (tid < 16) {
    lid_s[tid] = meta->valid[tid] ? meta->lids[tid] : -1;
    cls_s[tid] = meta->cls[tid];
  }
  __syncthreads();
  int t = blockIdx.x * 256 + tid;
  int p = t * 4;
  float4 lf = *(const float4*)(labf + p);
  int l4[4] = {__float_as_int(lf.x), __float_as_int(lf.y), __float_as_int(lf.z),
               __float_as_int(lf.w)};
  int cj[4];
#pragma unroll
  for (int j = 0; j < 4; ++j) {
    cj[j] = -1;
    int l = l4[j];
    if (l != BIGL) {
      for (int k = 0; k < 16; ++k)
        if (lid_s[k] == l) { cj[j] = cls_s[k]; break; }
    }
  }
#pragma unroll
  for (int c = 0; c < 4; ++c) {
    float4 w4 = make_float4(cj[0] == c ? 1.f : 0.f, cj[1] == c ? 1.f : 0.f,
                            cj[2] == c ? 1.f : 0.f, cj[3] == c ? 1.f : 0.f);
    *(float4*)(out + (size_t)c * HWTOT + p) = w4;
  }
}

extern "C" void kernel_launch(void* const* d_in, const int* in_sizes, int n_in,
                              void* d_out, int out_size, void* d_ws, size_t ws_size,
                              hipStream_t stream) {
  const float* x = (const float*)d_in[0];
  const float* w1 = (const float*)d_in[1];
  const float* w2 = (const float*)d_in[2];
  const float* w3 = (const float*)d_in[3];
  const float* cw1 = (const float*)d_in[4];
  const float* cw2 = (const float*)d_in[5];
  const float* fc = (const float*)d_in[6];

  char* base = (char*)d_out;
  int* lab_a = (int*)(base + OFF_LABA);
  int* lab_b = (int*)(base + OFF_LABB);
  float* rois = (float*)(base + OFF_ROIS);
  float* h1c = (float*)(base + OFF_H1C);
  float* h2c = (float*)(base + OFF_H2C);
  int2* cand = (int2*)(base + OFF_CAND);
  int* counts = (int*)(base + OFF_COUNTS);
  float* w2t = (float*)(base + OFF_W2T);
  int* list = (int*)(base + OFF_LIST);
  int* cand_count = (int*)d_ws;
  int* list_count = (int*)((char*)d_ws + 64);
  Meta* meta = (Meta*)((char*)d_ws + 256);

  hipMemsetAsync(counts, 0, (size_t)(HWTOT + 1) * sizeof(int), stream);
  hipMemsetAsync(d_ws, 0, 128, stream);

  prep_kernel<<<36, 256, 0, stream>>>(w2, w2t);
  cascade_kernel<<<dim3(64, 64), 256, 0, stream>>>(x, w1, w2t, w3, lab_a, list, list_count);
  recheck_kernel<<<2048, 256, 0, stream>>>(x, w1, w2, w3, list, list_count, lab_a);

  // 64 exact CC steps = 8 launches x 8 LDS-resident steps
  for (int l = 0; l < 8; ++l) {
    const int* src = (l & 1) ? lab_b : lab_a;
    int* dst = (l & 1) ? lab_a : lab_b;
    cc8_kernel<<<1024, 256, 0, stream>>>(src, dst);
  }
  // even # of launches -> final labels in lab_a

  hist_kernel<<<2048, 256, 0, stream>>>(lab_a, counts);
  cand_kernel<<<16384, 256, 0, stream>>>(counts, cand, cand_count);
  top16_kernel<<<1, 256, 0, stream>>>(cand, cand_count, meta);
  bbox_kernel<<<2048, 256, 0, stream>>>(lab_a, meta);
  roi_kernel<<<dim3(CSZ, 16), 256, 0, stream>>>(x, meta, rois);
  cconv1_kernel<<<dim3(56, 16), 256, 0, stream>>>(rois, cw1, meta, h1c);
  cconv2_kernel<<<dim3(27, 16), 256, 0, stream>>>(h1c, cw2, meta, h2c);
  poolfc_kernel<<<16, 256, 0, stream>>>(h2c, fc, meta);
  final_kernel<<<4096, 256, 0, stream>>>((const float*)d_out, meta, (float*)d_out);
}